// Round 7
// baseline (697.860 us; speedup 1.0000x reference)
//
#include <hip/hip_runtime.h>
#include <hip/hip_bf16.h>
#include <stdint.h>

#define IN_SZ 128
#define HID 128
#define OUT_SZ 67
#define SEQ 512
#define BATCH 2048
#define NTHR 128
#define SB (SEQ * BATCH)        // 1048576 elements
#define HSB (32u * SB)          // 32 rows of x stride

typedef __attribute__((ext_vector_type(4))) float f32x4;
typedef __attribute__((ext_vector_type(8))) short s16x8;
typedef __attribute__((ext_vector_type(8))) __bf16 bf16x8;

// setup-only scalar RNE
static __device__ __forceinline__ unsigned short f2bf(float f) {
  union { float f; uint32_t u; } c; c.f = f;
  uint32_t u = c.u;
  uint32_t r = u + 0x7FFFu + ((u >> 16) & 1u);
  return (unsigned short)(r >> 16);
}
// hot-loop packed convert -> v_cvt_pk_bf16_f32
static __device__ __forceinline__ uint32_t pk2bf(float lo, float hi) {
  __hip_bfloat162 h2 = __float22bfloat162_rn(float2{lo, hi});
  union { __hip_bfloat162 h; uint32_t u; } c; c.h = h2;
  return c.u;
}
static __device__ __forceinline__ void mfma16(f32x4& c, s16x8 a, s16x8 b) {
  c = __builtin_amdgcn_mfma_f32_16x16x32_bf16(
        __builtin_bit_cast(bf16x8, a), __builtin_bit_cast(bf16x8, b), c, 0, 0, 0);
}
// divide-free tanh: 1 - 2/(e^{2x}+1), e^{2x} = exp2(x * 2/ln2), rcp via v_rcp_f32
static __device__ __forceinline__ float fast_tanh(float x) {
  float e = __builtin_amdgcn_exp2f(x * 2.885390081777927f);
  float r = __builtin_amdgcn_rcpf(e + 1.f);
  return __builtin_fmaf(-2.f, r, 1.f);
}
// B/A fragment k-offset for slot j (HW-verified R1-R6)
#define KOFF(g, j) (4 * (g) + ((j) & 3) + (((j) >> 2) << 4))

// lgkm-only barrier: x loads / Y stores float across steps (no vmcnt drain)
static __device__ __forceinline__ void sync_lds() {
  __builtin_amdgcn_sched_barrier(0);
  asm volatile("s_waitcnt lgkmcnt(0)\n\ts_barrier" ::: "memory");
  __builtin_amdgcn_sched_barrier(0);
}

__global__ __launch_bounds__(NTHR, 1) void rnn_kernel(
    const float* __restrict__ x, const float* __restrict__ hidden,
    const float* __restrict__ mask, const float* __restrict__ Wi2h,
    const float* __restrict__ bi2h, const float* __restrict__ Wi2o,
    const float* __restrict__ bi2o, float* __restrict__ Y,
    float* __restrict__ wsf) {

  // frag store: [buf][0..3 = x kk, 4..7 = h kk][lane]; wO/bias constants in LDS
  __shared__ s16x8 sF[2][8][64];
  __shared__ s16x8 sWO[6][4][64];
  __shared__ float sBH[8][16];
  __shared__ float sBO[6][16];

  const int tid = threadIdx.x;
  const int wave = tid >> 6;          // 0..1; owns M-tiles 4w..4w+3, h/x frags 2w,2w+1
  const int lane = tid & 63;
  const int g = lane >> 4;
  const int n16 = lane & 15;
  const int b0 = blockIdx.x * 16;

  // ---- Wi2h A-frags, tiles 4w..4w+3 (128 VGPR), single bf16 ----
  s16x8 W[4][8];
#pragma unroll
  for (int tl = 0; tl < 4; ++tl) {
    const float* wrow = Wi2h + (size_t)(16 * (4 * wave + tl) + n16) * (IN_SZ + HID);
#pragma unroll
    for (int kt = 0; kt < 8; ++kt) {
      s16x8 w8;
#pragma unroll
      for (int j = 0; j < 8; ++j)
        w8[j] = (short)f2bf(wrow[32 * kt + KOFF(g, j)]);
      W[tl][kt] = w8;
    }
  }

  // ---- wO frags -> LDS (6 out-tiles; rows >= 67 zeroed; tile 5 all zero) ----
#pragma unroll
  for (int ot = 0; ot < 3; ++ot) {
    int tk = 3 * wave + ot;
    int m = 16 * tk + n16;
#pragma unroll
    for (int kk = 0; kk < 4; ++kk) {
      s16x8 o8;
#pragma unroll
      for (int j = 0; j < 8; ++j)
        o8[j] = (short)((m < OUT_SZ) ? f2bf(Wi2o[(size_t)m * HID + 32 * kk + KOFF(g, j)]) : 0);
      sWO[tk][kk][lane] = o8;
    }
  }
  // biases -> LDS
  { int tile = tid >> 4, row = tid & 15; sBH[tile][row] = bi2h[16 * tile + row]; }
  if (tid < 96) {
    int tk = tid >> 4, row = tid & 15, m = 16 * tk + row;
    sBO[tk][row] = (m < OUT_SZ) ? bi2o[m] : 0.f;
  }

  // ---- x element-offset bases (8; second half via +HSB uniform) ----
  uint32_t bx[8];
#pragma unroll
  for (int j = 0; j < 8; ++j)
    bx[j] = (uint32_t)(64 * wave + KOFF(g, j)) * SB + (uint32_t)(b0 + n16);

  // ---- Y address bases + validity ----
  uint32_t yb[3];
  int mrow[3];
#pragma unroll
  for (int ot = 0; ot < 3; ++ot) {
    int tk = 3 * wave + ot;
    yb[ot] = (uint32_t)(16 * tk + 4 * g) * SB + (uint32_t)(b0 + n16);
    mrow[ot] = 16 * tk + 4 * g;
  }
  float* const sink = wsf + ((blockIdx.x & 127) << 6) + (tid & 63);

  // ---- stage x_0, h_0 frags (own kk = 2w+hf) into buf 0 ----
#pragma unroll
  for (int hf = 0; hf < 2; ++hf) {
    float xv[8], hv[8];
#pragma unroll
    for (int j = 0; j < 8; ++j) {
      uint32_t off = bx[j] + hf * HSB;
      xv[j] = x[(size_t)off];
      uint32_t hrow = (uint32_t)(64 * wave + KOFF(g, j) + 32 * hf);
      uint32_t hoff = hrow * BATCH + (uint32_t)(b0 + n16);
      hv[j] = hidden[(size_t)hoff] * mask[(size_t)hoff];
    }
    union { s16x8 v; uint32_t d[4]; } ux, uh;
#pragma unroll
    for (int q = 0; q < 4; ++q) {
      ux.d[q] = pk2bf(xv[2 * q], xv[2 * q + 1]);
      uh.d[q] = pk2bf(hv[2 * q], hv[2 * q + 1]);
    }
    sF[0][2 * wave + hf][lane] = ux.v;
    sF[0][4 + 2 * wave + hf][lane] = uh.v;
  }

  // ---- 3-deep raw x prefetch: xc0 = x_1, xc1 = x_2 ----
  float xc0[16], xc1[16];
#pragma unroll
  for (int v = 0; v < 16; ++v) {
    uint32_t base = bx[v & 7] + (v >> 3) * HSB;
    xc0[v] = x[(size_t)(base + 1u * BATCH)];
    xc1[v] = x[(size_t)(base + 2u * BATCH)];
  }
  sync_lds();

  for (int t = 0; t < SEQ; ++t) {
    const int p = t & 1;
    // issue x_{t+3} loads (clamped, branchless)
    const uint32_t toff3 = (uint32_t)((t + 3 > 511) ? 511 : t + 3) * BATCH;
    float xn[16];
#pragma unroll
    for (int v = 0; v < 16; ++v)
      xn[v] = x[(size_t)(bx[v & 7] + (v >> 3) * HSB + toff3)];

    // read all frags of [x_t ; h_t]
    s16x8 X0 = sF[p][0][lane], X1 = sF[p][1][lane];
    s16x8 X2 = sF[p][2][lane], X3 = sF[p][3][lane];
    s16x8 H0 = sF[p][4][lane], H1 = sF[p][5][lane];
    s16x8 H2 = sF[p][6][lane], H3 = sF[p][7][lane];

    // ---- i2h + tanh, tile-pairs; D-frag(pair) == B-frag kk (identity repack) ----
#pragma unroll
    for (int pr = 0; pr < 2; ++pr) {
      const int tl0 = 2 * pr, tl1 = 2 * pr + 1;
      f32x4 a  = *(const f32x4*)&sBH[4 * wave + tl0][4 * g], a2 = {0, 0, 0, 0};
      f32x4 b  = *(const f32x4*)&sBH[4 * wave + tl1][4 * g], b2 = {0, 0, 0, 0};
      mfma16(a, W[tl0][0], X0);  mfma16(a2, W[tl0][1], X1);
      mfma16(b, W[tl1][0], X0);  mfma16(b2, W[tl1][1], X1);
      mfma16(a, W[tl0][2], X2);  mfma16(a2, W[tl0][3], X3);
      mfma16(b, W[tl1][2], X2);  mfma16(b2, W[tl1][3], X3);
      mfma16(a, W[tl0][4], H0);  mfma16(a2, W[tl0][5], H1);
      mfma16(b, W[tl1][4], H0);  mfma16(b2, W[tl1][5], H1);
      mfma16(a, W[tl0][6], H2);  mfma16(a2, W[tl0][7], H3);
      mfma16(b, W[tl1][6], H2);  mfma16(b2, W[tl1][7], H3);
      f32x4 s0 = a + a2, s1 = b + b2;
      union { s16x8 v; uint32_t d[4]; } u;
      u.d[0] = pk2bf(fast_tanh(s0[0]), fast_tanh(s0[1]));
      u.d[1] = pk2bf(fast_tanh(s0[2]), fast_tanh(s0[3]));
      u.d[2] = pk2bf(fast_tanh(s1[0]), fast_tanh(s1[1]));
      u.d[3] = pk2bf(fast_tanh(s1[2]), fast_tanh(s1[3]));
      sF[p ^ 1][4 + 2 * wave + pr][lane] = u.v;
    }

    // ---- x_{t+1} frags from xc0 (loaded 2 steps ago; latency fully hidden) ----
#pragma unroll
    for (int hf = 0; hf < 2; ++hf) {
      union { s16x8 v; uint32_t d[4]; } u;
#pragma unroll
      for (int q = 0; q < 4; ++q)
        u.d[q] = pk2bf(xc0[8 * hf + 2 * q], xc0[8 * hf + 2 * q + 1]);
      sF[p ^ 1][2 * wave + hf][lane] = u.v;
    }

    // ---- i2o: y_{t-1} = relu(Wo·h_t + bo); unconditional stores, sink for dead ----
    const uint32_t toffm1 = (uint32_t)t * BATCH - (uint32_t)BATCH;  // unused when t==0
#pragma unroll
    for (int ot = 0; ot < 3; ++ot) {
      const int tk = 3 * wave + ot;
      f32x4 ao = *(const f32x4*)&sBO[tk][4 * g];
      mfma16(ao, sWO[tk][0][lane], H0);
      mfma16(ao, sWO[tk][1][lane], H1);
      mfma16(ao, sWO[tk][2][lane], H2);
      mfma16(ao, sWO[tk][3][lane], H3);
#pragma unroll
      for (int r = 0; r < 4; ++r) {
        const bool ok = (mrow[ot] + r < OUT_SZ) & (t > 0);
        float* dst = ok ? (Y + (size_t)(yb[ot] + (uint32_t)r * SB + toffm1)) : sink;
        *dst = fmaxf(ao[r], 0.f);
      }
    }

    // rotate raw x buffers
#pragma unroll
    for (int v = 0; v < 16; ++v) { xc0[v] = xc1[v]; xc1[v] = xn[v]; }

    sync_lds();   // publish buf p^1 (LDS-only drain)
  }

  // ---- epilogue: y_511 = relu(Wo·h_512 + bo); h_512 frags in buf 0 ----
  {
    s16x8 H0 = sF[0][4][lane], H1 = sF[0][5][lane];
    s16x8 H2 = sF[0][6][lane], H3 = sF[0][7][lane];
    const uint32_t toffm1 = 511u * BATCH;
#pragma unroll
    for (int ot = 0; ot < 3; ++ot) {
      const int tk = 3 * wave + ot;
      f32x4 ao = *(const f32x4*)&sBO[tk][4 * g];
      mfma16(ao, sWO[tk][0][lane], H0);
      mfma16(ao, sWO[tk][1][lane], H1);
      mfma16(ao, sWO[tk][2][lane], H2);
      mfma16(ao, sWO[tk][3][lane], H3);
#pragma unroll
      for (int r = 0; r < 4; ++r) {
        const bool ok = (mrow[ot] + r < OUT_SZ);
        float* dst = ok ? (Y + (size_t)(yb[ot] + (uint32_t)r * SB + toffm1)) : sink;
        *dst = fmaxf(ao[r], 0.f);
      }
    }
  }
}

extern "C" void kernel_launch(void* const* d_in, const int* in_sizes, int n_in,
                              void* d_out, int out_size, void* d_ws, size_t ws_size,
                              hipStream_t stream) {
  const float* x      = (const float*)d_in[0];
  const float* hidden = (const float*)d_in[1];
  const float* mask   = (const float*)d_in[2];
  const float* Wi2h   = (const float*)d_in[3];
  const float* bi2h   = (const float*)d_in[4];
  const float* Wi2o   = (const float*)d_in[5];
  const float* bi2o   = (const float*)d_in[6];
  float* Y = (float*)d_out;
  (void)in_sizes; (void)n_in; (void)out_size; (void)ws_size;
  rnn_kernel<<<dim3(BATCH / 16), dim3(NTHR), 0, stream>>>(
      x, hidden, mask, Wi2h, bi2h, Wi2o, bi2o, Y, (float*)d_ws);
}